// Round 8
// baseline (198.976 us; speedup 1.0000x reference)
//
#include <hip/hip_runtime.h>
#include <hip/hip_fp16.h>

// DCNv2 R8: barrier-free k_fused via wave-private tap tiles.
//   Each wave owns 16 px and ALL 128 outputs for them. Per tap: coalesced
//   broadcast gather (R5-validated), blend, write to the wave's private
//   4.25KB LDS strip, s_waitcnt lgkmcnt(0) (NO __syncthreads), 4 b128
//   B-fragment reads, 32 MFMAs (8 o-blocks x 4 k-slices). Waves free-run.
//   offout prefetched 1 tap ahead. S strip rows padded to 68 words.

typedef unsigned int u32;
typedef __attribute__((ext_vector_type(8))) _Float16 f16x8;
typedef __attribute__((ext_vector_type(4))) float f32x4;

union U16 { uint4 u; f16x8 h; };
union H2U { __half2 h2; u32 u; };

static __device__ __forceinline__ u32 pkh(float a, float b) {
    H2U c; c.h2 = __float22half2_rn(make_float2(a, b)); return c.u;
}
static __device__ __forceinline__ u32 pkw(float w) {
    __half h = __float2half_rn(w);
    H2U c; c.h2 = __half2(h, h); return c.u;
}
static __device__ __forceinline__ u32 hfma2u(u32 a, u32 w, u32 acc) {
    H2U x, y, z; x.u = a; y.u = w; z.u = acc;
    z.h2 = __hfma2(x.h2, y.h2, z.h2); return z.u;
}
static __device__ __forceinline__ u32 hmul2u(u32 a, u32 w) {
    H2U x, y; x.u = a; y.u = w;
    y.h2 = __hmul2(x.h2, y.h2); return y.u;
}

#define B_   16
#define HW_  4096
#define CU_  64          // 128 ch = 64 fp16-pair words

// ---------------- kernel 1: NCHW f32 -> NHWC fp16 ----------------
__global__ __launch_bounds__(256) void k_transpose(const float* __restrict__ x,
                                                   u32* __restrict__ xtu) {
    __shared__ float tile[32][129];
    int blk = blockIdx.x, t = threadIdx.x;
    int b = blk >> 7, hw0 = (blk & 127) << 5;
    int hwl = t & 31, cg = t >> 5;
    const float* src = x + (size_t)b * 128 * HW_ + hw0 + hwl;
#pragma unroll
    for (int i = 0; i < 16; ++i) { int c = cg + (i << 3); tile[hwl][c] = src[(size_t)c * HW_]; }
    __syncthreads();
    u32* dst = xtu + ((size_t)b * HW_ + hw0) * CU_;
    int u = t & 63, hq = t >> 6;
#pragma unroll
    for (int j = 0; j < 8; ++j) {
        int hw = (hq << 3) + j;
        dst[(size_t)hw * CU_ + u] = pkh(tile[hw][2 * u], tile[hw][2 * u + 1]);
    }
}

// ---------------- kernel 2: weight prep ----------------
__global__ __launch_bounds__(256) void k_prep(const float* __restrict__ weight,
                                              const float* __restrict__ off_w,
                                              u32* __restrict__ wtu,
                                              u32* __restrict__ woffu) {
    int idx = blockIdx.x * 256 + threadIdx.x;
    if (idx < 73728) {
        int o = idx / 576, r = idx % 576;
        int n = r / 64, cu = r % 64, c = cu * 2;
        float a = weight[((size_t)(o * 128 + c)) * 9 + n];
        float b = weight[((size_t)(o * 128 + c + 1)) * 9 + n];
        wtu[idx] = pkh(a, b);
    } else if (idx < 73728 + 18432) {
        int k = idx - 73728;
        int o = k / 576, r = k % 576;
        int tap = r / 64, cu = r % 64, c = cu * 2;
        u32 v = 0u;
        if (o < 27) {
            float a = off_w[((size_t)(o * 128 + c)) * 9 + tap];
            float b = off_w[((size_t)(o * 128 + c + 1)) * 9 + tap];
            v = pkh(a, b);
        }
        woffu[k] = v;
    }
}

// ---------------- kernel 3: offset/mask conv via MFMA ----------------
__global__ __launch_bounds__(256) void k_offconv(const u32* __restrict__ xtu,
                                                 const u32* __restrict__ woffu,
                                                 const float* __restrict__ off_b,
                                                 float* __restrict__ offout) {
    __shared__ __align__(16) u32 S[3][64][64];
    int blk = ((blockIdx.x & 7) << 7) + (blockIdx.x >> 3);   // XCD-chunked
    int t = threadIdx.x;
    int b = blk >> 6, ho = blk & 63;
    const u32* xb = xtu + (size_t)b * HW_ * CU_;
    const uint4 z4 = {0u, 0u, 0u, 0u};
#pragma unroll
    for (int i = 0; i < 12; ++i) {
        int li = t + (i << 8);
        int r = li >> 10, rem = li & 1023;
        int px = rem >> 4, ch = rem & 15;
        int yy = ho + r - 1;
        uint4 v = ((unsigned)yy < 64u) ? *(const uint4*)(xb + ((yy << 6) + px) * CU_ + (ch << 2)) : z4;
        *(uint4*)&S[r][px][(ch ^ (px & 7)) << 2] = v;
    }
    __syncthreads();
    int lane = t & 63, w = t >> 6, l15 = lane & 15, lhi = lane >> 4;
    int ob = w >> 1, pb0 = (w & 1) << 1;
    f32x4 acc[2];
    acc[0] = (f32x4){0.f, 0.f, 0.f, 0.f};
    acc[1] = (f32x4){0.f, 0.f, 0.f, 0.f};
#pragma unroll 1
    for (int tap = 0; tap < 9; ++tap) {
        int ky = tap / 3, kx = tap % 3;
        int yy = ho + ky - 1;
        if ((unsigned)yy >= 64u) continue;
        U16 af[4];
#pragma unroll
        for (int ks = 0; ks < 4; ++ks)
            af[ks].u = *(const uint4*)(woffu + (size_t)(ob * 16 + l15) * 576
                                       + tap * 64 + ks * 16 + lhi * 4);
#pragma unroll
        for (int pp = 0; pp < 2; ++pp) {
            int pr = ((pb0 + pp) << 4) + l15;
            int pxs = pr + kx - 1;
            bool v = (unsigned)pxs < 64u;
            int pxc = v ? pxs : 0;
#pragma unroll
            for (int ks = 0; ks < 4; ++ks) {
                U16 sf;
                sf.u = v ? *(const uint4*)&S[ky][pxc][((ks * 4 + lhi) ^ (pxc & 7)) << 2] : z4;
                acc[pp] = __builtin_amdgcn_mfma_f32_16x16x32_f16(af[ks].h, sf.h, acc[pp], 0, 0, 0);
            }
        }
    }
    float* dst = offout + (size_t)b * 27 * HW_ + (ho << 6);
#pragma unroll
    for (int pp = 0; pp < 2; ++pp)
#pragma unroll
        for (int r = 0; r < 4; ++r) {
            int o = ob * 16 + lhi * 4 + r;
            if (o < 27) {
                float s = acc[pp][r] + off_b[o];
                if (o >= 18) s = 1.f / (1.f + __expf(-s));
                dst[(size_t)o * HW_ + ((pb0 + pp) << 4) + l15] = s;
            }
        }
}

// ---------------- kernel 4: fused sample + MFMA, wave-private, no barriers ----
__global__ __launch_bounds__(256, 4) void k_fused(const u32* __restrict__ xtu,
                                                  const float* __restrict__ offout,
                                                  const u32* __restrict__ wtu,
                                                  const float* __restrict__ bias,
                                                  float* __restrict__ out) {
    __shared__ __align__(16) u32 S[4][16][68];   // per-wave strips, 17.4 KB
    int blk = ((blockIdx.x & 7) << 7) + (blockIdx.x >> 3);   // XCD-chunked
    int t = threadIdx.x;
    int b = blk >> 6, ho = blk & 63;
    int w = t >> 6, lane = t & 63, l15 = lane & 15, lhi = lane >> 4;
    int pxa = (w << 4) + l15;        // pixel this lane owns params for

    f32x4 acc[8];
#pragma unroll
    for (int ob = 0; ob < 8; ++ob) acc[ob] = (f32x4){0.f, 0.f, 0.f, 0.f};

    const float* offb = offout + (size_t)b * 27 * HW_ + ho * 64 + pxa;
    const u32* xb = xtu + (size_t)b * HW_ * CU_;

    float pdy = offb[0], pdx = offb[(size_t)HW_], pm = offb[(size_t)18 * HW_];

#pragma unroll 1
    for (int n = 0; n < 9; ++n) {
        // --- prefetch next tap's offsets ---
        float qdy = 0.f, qdx = 0.f, qm = 0.f;
        if (n < 8) {
            qdy = offb[(size_t)(2 * n + 2) * HW_];
            qdx = offb[(size_t)(2 * n + 3) * HW_];
            qm  = offb[(size_t)(19 + n) * HW_];
        }
        // --- params for this tap (per-lane pixel pxa) ---
        float ys = (float)(ho + n / 3 - 1) + pdy;
        float xs = (float)(pxa + n % 3 - 1) + pdx;
        float y0f = floorf(ys), x0f = floorf(xs);
        float fy = ys - y0f, fx = xs - x0f;
        int y0 = (int)y0f, x0 = (int)x0f;
        bool vy0 = (unsigned)y0 < 64u, vy1 = (unsigned)(y0 + 1) < 64u;
        bool vx0 = (unsigned)x0 < 64u, vx1 = (unsigned)(x0 + 1) < 64u;
        u32 u00 = pkw((vy0 && vx0) ? (1.f - fy) * (1.f - fx) * pm : 0.f);
        u32 u01 = pkw((vy0 && vx1) ? (1.f - fy) * fx * pm : 0.f);
        u32 u10 = pkw((vy1 && vx0) ? fy * (1.f - fx) * pm : 0.f);
        u32 u11 = pkw((vy1 && vx1) ? fy * fx * pm : 0.f);
        int y0c = min(max(y0, 0), 63), y1c = min(max(y0 + 1, 0), 63);
        int x0c = min(max(x0, 0), 63), x1c = min(max(x0 + 1, 0), 63);
        int ca00 = (y0c << 12) + (x0c << 6);
        int ca11 = (y1c << 12) + (x1c << 6);
        // --- gather + blend own 16 px, 2 groups of 8 (coalesced broadcast) ---
#pragma unroll
        for (int g = 0; g < 2; ++g) {
            u32 ld[8][4];
#pragma unroll
            for (int j = 0; j < 8; ++j) {
                int jj = (g << 3) + j + (w << 4);       // lane index of param owner
                int sa00 = __builtin_amdgcn_readlane(ca00, jj & 63);
                int sa11 = __builtin_amdgcn_readlane(ca11, jj & 63);
                int sa01 = (sa00 & ~0xFFF) | (sa11 & 0xFFF);
                int sa10 = (sa11 & ~0xFFF) | (sa00 & 0xFFF);
                ld[j][0] = xb[sa00 + lane];  ld[j][1] = xb[sa01 + lane];
                ld[j][2] = xb[sa10 + lane];  ld[j][3] = xb[sa11 + lane];
            }
#pragma unroll
            for (int j = 0; j < 8; ++j) {
                int jj = (g << 3) + j + (w << 4);
                u32 s0 = (u32)__builtin_amdgcn_readlane((int)u00, jj & 63);
                u32 s1 = (u32)__builtin_amdgcn_readlane((int)u01, jj & 63);
                u32 s2 = (u32)__builtin_amdgcn_readlane((int)u10, jj & 63);
                u32 s3 = (u32)__builtin_amdgcn_readlane((int)u11, jj & 63);
                u32 r = hfma2u(ld[j][3], s3, hfma2u(ld[j][2], s2,
                        hfma2u(ld[j][1], s1, hmul2u(ld[j][0], s0))));
                S[w][(g << 3) + j][lane] = r;
            }
        }
        // --- wave-local fence: LDS writes visible to all lanes of this wave ---
        asm volatile("s_waitcnt lgkmcnt(0)" ::: "memory");
        __builtin_amdgcn_sched_barrier(0);
        // --- B fragments from own strip, then 32 MFMAs ---
        U16 sf[4];
#pragma unroll
        for (int ks = 0; ks < 4; ++ks)
            sf[ks].u = *(const uint4*)&S[w][l15][(ks * 4 + lhi) << 2];
#pragma unroll
        for (int ob = 0; ob < 8; ++ob) {
            const u32* wrow = wtu + (size_t)(ob * 16 + l15) * 576 + n * 64 + lhi * 4;
#pragma unroll
            for (int ks = 0; ks < 4; ++ks) {
                U16 af; af.u = *(const uint4*)(wrow + ks * 16);
                acc[ob] = __builtin_amdgcn_mfma_f32_16x16x32_f16(
                    af.h, sf[ks].h, acc[ob], 0, 0, 0);
            }
        }
        pdy = qdy; pdx = qdx; pm = qm;
    }
    // --- epilogue: o = ob*16+lhi*4+r, px = (w<<4)+l15 ---
    float* ob_base = out + (size_t)b * 128 * HW_ + ho * 64 + (w << 4);
#pragma unroll
    for (int ob = 0; ob < 8; ++ob)
#pragma unroll
        for (int r = 0; r < 4; ++r) {
            int o = ob * 16 + lhi * 4 + r;
            ob_base[(size_t)o * HW_ + l15] = acc[ob][r] + bias[o];
        }
}

extern "C" void kernel_launch(void* const* d_in, const int* in_sizes, int n_in,
                              void* d_out, int out_size, void* d_ws, size_t ws_size,
                              hipStream_t stream) {
    const float* x      = (const float*)d_in[0];
    const float* weight = (const float*)d_in[1];
    const float* bias   = (const float*)d_in[2];
    const float* off_w  = (const float*)d_in[3];
    const float* off_b  = (const float*)d_in[4];
    float* out = (float*)d_out;

    u32*   xtu    = (u32*)d_ws;
    float* offout = (float*)(xtu + (size_t)B_ * HW_ * CU_);
    u32*   wtu    = (u32*)(offout + (size_t)B_ * 27 * HW_);
    u32*   woffu  = wtu + 73728;

    hipLaunchKernelGGL(k_transpose, dim3(2048), dim3(256), 0, stream, x, xtu);
    hipLaunchKernelGGL(k_prep, dim3((73728 + 18432 + 255) / 256), dim3(256), 0, stream,
                       weight, off_w, wtu, woffu);
    hipLaunchKernelGGL(k_offconv, dim3(1024), dim3(256), 0, stream, xtu, woffu, off_b, offout);
    hipLaunchKernelGGL(k_fused, dim3(1024), dim3(256), 0, stream, xtu, offout, wtu, bias, out);
}

// Round 9
// 118.466 us; speedup vs baseline: 1.6796x; 1.6796x over previous
//
#include <hip/hip_runtime.h>
#include <hip/hip_fp16.h>

// DCNv2 R9: readlane-free params + coalesced W-fragments.
//   k_transpose: x NCHW f32 -> NHWC fp16 pairs (xtu)
//   k_prep:      wtv[((n*4+ks)*8+og)*64 + lane] uint4 W-fragments (coalesced MFMA A);
//                woffu[32][576] for offconv
//   k_offconv:   unchanged (R3-validated MFMA conv)
//   k_params:    per (b,px,tap): paramsW uint4 = 4x (w,w) fp16 pairs (mask folded),
//                paramsA uint2 = byte addrs of corners 00/11 (01/10 via bit-splice)
//   k_fused:     R5 structure; per tap: 16 uniform param loads, 64 coalesced
//                gather loads, 64 v_pk_fma_f16, 16 LDS writes, barrier, MFMA.

typedef unsigned int u32;
typedef __attribute__((ext_vector_type(8))) _Float16 f16x8;
typedef __attribute__((ext_vector_type(4))) float f32x4;

union U16 { uint4 u; f16x8 h; };
union H2U { __half2 h2; u32 u; };

static __device__ __forceinline__ u32 pkh(float a, float b) {
    H2U c; c.h2 = __float22half2_rn(make_float2(a, b)); return c.u;
}
static __device__ __forceinline__ u32 pkw(float w) {
    __half h = __float2half_rn(w);
    H2U c; c.h2 = __half2(h, h); return c.u;
}
static __device__ __forceinline__ u32 hfma2u(u32 a, u32 w, u32 acc) {
    H2U x, y, z; x.u = a; y.u = w; z.u = acc;
    z.h2 = __hfma2(x.h2, y.h2, z.h2); return z.u;
}
static __device__ __forceinline__ u32 hmul2u(u32 a, u32 w) {
    H2U x, y; x.u = a; y.u = w;
    y.h2 = __hmul2(x.h2, y.h2); return y.u;
}

#define B_   16
#define HW_  4096
#define CU_  64          // 128 ch = 64 fp16-pair words

// ---------------- kernel 1: NCHW f32 -> NHWC fp16 ----------------
__global__ __launch_bounds__(256) void k_transpose(const float* __restrict__ x,
                                                   u32* __restrict__ xtu) {
    __shared__ float tile[32][129];
    int blk = blockIdx.x, t = threadIdx.x;
    int b = blk >> 7, hw0 = (blk & 127) << 5;
    int hwl = t & 31, cg = t >> 5;
    const float* src = x + (size_t)b * 128 * HW_ + hw0 + hwl;
#pragma unroll
    for (int i = 0; i < 16; ++i) { int c = cg + (i << 3); tile[hwl][c] = src[(size_t)c * HW_]; }
    __syncthreads();
    u32* dst = xtu + ((size_t)b * HW_ + hw0) * CU_;
    int u = t & 63, hq = t >> 6;
#pragma unroll
    for (int j = 0; j < 8; ++j) {
        int hw = (hq << 3) + j;
        dst[(size_t)hw * CU_ + u] = pkh(tile[hw][2 * u], tile[hw][2 * u + 1]);
    }
}

// ---------------- kernel 2: weight prep ----------------
// wtv: uint4[18432]: [((n*4+ks)*8+og)*64 + lane] = pairs of W[og*16+(lane&15)]
//      [ks*32+(lane>>4)*8 .. +8][n]   (coalesced per-wave A-fragment load)
// woffu: [32][576] pair idx = tap*64+cu (rows 27..31 zero)
__global__ __launch_bounds__(256) void k_prep(const float* __restrict__ weight,
                                              const float* __restrict__ off_w,
                                              uint4* __restrict__ wtv,
                                              u32* __restrict__ woffu) {
    int idx = blockIdx.x * 256 + threadIdx.x;
    if (idx < 18432) {
        int l = idx & 63, og = (idx >> 6) & 7, ks = (idx >> 9) & 3, n = idx >> 11;
        int o = og * 16 + (l & 15);
        int c0 = ks * 32 + (l >> 4) * 8;
        u32 r[4];
#pragma unroll
        for (int q = 0; q < 4; ++q) {
            int c = c0 + 2 * q;
            r[q] = pkh(weight[((size_t)(o * 128 + c)) * 9 + n],
                       weight[((size_t)(o * 128 + c + 1)) * 9 + n]);
        }
        wtv[idx] = make_uint4(r[0], r[1], r[2], r[3]);
    } else {
        int k = idx - 18432;
        int o = k / 576, r = k % 576;
        int tap = r / 64, cu = r % 64, c = cu * 2;
        u32 v = 0u;
        if (o < 27) {
            float a = off_w[((size_t)(o * 128 + c)) * 9 + tap];
            float b = off_w[((size_t)(o * 128 + c + 1)) * 9 + tap];
            v = pkh(a, b);
        }
        woffu[k] = v;
    }
}

// ---------------- kernel 3: offset/mask conv via MFMA ----------------
__global__ __launch_bounds__(256) void k_offconv(const u32* __restrict__ xtu,
                                                 const u32* __restrict__ woffu,
                                                 const float* __restrict__ off_b,
                                                 float* __restrict__ offout) {
    __shared__ __align__(16) u32 S[3][64][64];
    int blk = ((blockIdx.x & 7) << 7) + (blockIdx.x >> 3);   // XCD-chunked
    int t = threadIdx.x;
    int b = blk >> 6, ho = blk & 63;
    const u32* xb = xtu + (size_t)b * HW_ * CU_;
    const uint4 z4 = {0u, 0u, 0u, 0u};
#pragma unroll
    for (int i = 0; i < 12; ++i) {
        int li = t + (i << 8);
        int r = li >> 10, rem = li & 1023;
        int px = rem >> 4, ch = rem & 15;
        int yy = ho + r - 1;
        uint4 v = ((unsigned)yy < 64u) ? *(const uint4*)(xb + ((yy << 6) + px) * CU_ + (ch << 2)) : z4;
        *(uint4*)&S[r][px][(ch ^ (px & 7)) << 2] = v;
    }
    __syncthreads();
    int lane = t & 63, w = t >> 6, l15 = lane & 15, lhi = lane >> 4;
    int ob = w >> 1, pb0 = (w & 1) << 1;
    f32x4 acc[2];
    acc[0] = (f32x4){0.f, 0.f, 0.f, 0.f};
    acc[1] = (f32x4){0.f, 0.f, 0.f, 0.f};
#pragma unroll 1
    for (int tap = 0; tap < 9; ++tap) {
        int ky = tap / 3, kx = tap % 3;
        int yy = ho + ky - 1;
        if ((unsigned)yy >= 64u) continue;
        U16 af[4];
#pragma unroll
        for (int ks = 0; ks < 4; ++ks)
            af[ks].u = *(const uint4*)(woffu + (size_t)(ob * 16 + l15) * 576
                                       + tap * 64 + ks * 16 + lhi * 4);
#pragma unroll
        for (int pp = 0; pp < 2; ++pp) {
            int pr = ((pb0 + pp) << 4) + l15;
            int pxs = pr + kx - 1;
            bool v = (unsigned)pxs < 64u;
            int pxc = v ? pxs : 0;
#pragma unroll
            for (int ks = 0; ks < 4; ++ks) {
                U16 sf;
                sf.u = v ? *(const uint4*)&S[ky][pxc][((ks * 4 + lhi) ^ (pxc & 7)) << 2] : z4;
                acc[pp] = __builtin_amdgcn_mfma_f32_16x16x32_f16(af[ks].h, sf.h, acc[pp], 0, 0, 0);
            }
        }
    }
    float* dst = offout + (size_t)b * 27 * HW_ + (ho << 6);
#pragma unroll
    for (int pp = 0; pp < 2; ++pp)
#pragma unroll
        for (int r = 0; r < 4; ++r) {
            int o = ob * 16 + lhi * 4 + r;
            if (o < 27) {
                float s = acc[pp][r] + off_b[o];
                if (o >= 18) s = 1.f / (1.f + __expf(-s));
                dst[(size_t)o * HW_ + ((pb0 + pp) << 4) + l15] = s;
            }
        }
}

// ---------------- kernel 3.5: pack per-sample params ----------------
__global__ __launch_bounds__(256) void k_params(const float* __restrict__ offout,
                                                uint4* __restrict__ paramsW,
                                                uint2* __restrict__ paramsA) {
    int g = blockIdx.x * 256 + threadIdx.x;    // 589824 total
    int wo = g & 63, r = g >> 6;
    int tap = r % 9, bho = r / 9;
    int ho = bho & 63, b = bho >> 6;
    const float* ob_ = offout + (size_t)b * 27 * HW_ + ho * 64 + wo;
    float dy = ob_[(size_t)(2 * tap) * HW_];
    float dx = ob_[(size_t)(2 * tap + 1) * HW_];
    float m  = ob_[(size_t)(18 + tap) * HW_];
    float ys = (float)(ho + tap / 3 - 1) + dy;
    float xs = (float)(wo + tap % 3 - 1) + dx;
    float y0f = floorf(ys), x0f = floorf(xs);
    float fy = ys - y0f, fx = xs - x0f;
    int y0 = (int)y0f, x0 = (int)x0f;
    bool vy0 = (unsigned)y0 < 64u, vy1 = (unsigned)(y0 + 1) < 64u;
    bool vx0 = (unsigned)x0 < 64u, vx1 = (unsigned)(x0 + 1) < 64u;
    u32 w00 = pkw((vy0 && vx0) ? (1.f - fy) * (1.f - fx) * m : 0.f);
    u32 w01 = pkw((vy0 && vx1) ? (1.f - fy) * fx * m : 0.f);
    u32 w10 = pkw((vy1 && vx0) ? fy * (1.f - fx) * m : 0.f);
    u32 w11 = pkw((vy1 && vx1) ? fy * fx * m : 0.f);
    int y0c = min(max(y0, 0), 63), y1c = min(max(y0 + 1, 0), 63);
    int x0c = min(max(x0, 0), 63), x1c = min(max(x0 + 1, 0), 63);
    u32 a00 = ((u32)y0c << 14) + ((u32)x0c << 8);   // byte addrs within batch slice
    u32 a11 = ((u32)y1c << 14) + ((u32)x1c << 8);
    paramsW[g] = make_uint4(w00, w01, w10, w11);
    paramsA[g] = make_uint2(a00, a11);
}

// ---------------- kernel 4: fused sample + MFMA ----------------
__global__ __launch_bounds__(256, 4) void k_fused(const u32* __restrict__ xtu,
                                                  const uint4* __restrict__ wtv,
                                                  const uint4* __restrict__ paramsW,
                                                  const uint2* __restrict__ paramsA,
                                                  const float* __restrict__ bias,
                                                  float* __restrict__ out) {
    __shared__ __align__(16) u32 S[2][64][68];   // dbuf, 68-word rows
    int blk = ((blockIdx.x & 7) << 7) + (blockIdx.x >> 3);   // XCD-chunked
    int t = threadIdx.x;
    int b = blk >> 6, ho = blk & 63;
    int w = t >> 6, lane = t & 63, l15 = lane & 15, lhi = lane >> 4;
    int o0 = w * 32;
    int lane4 = lane << 2;

    f32x4 acc[2][4];
#pragma unroll
    for (int ob = 0; ob < 2; ++ob)
#pragma unroll
        for (int pb = 0; pb < 4; ++pb) acc[ob][pb] = (f32x4){0.f, 0.f, 0.f, 0.f};

    const char* xbb = (const char*)(xtu + (size_t)b * HW_ * CU_);
    int pbase = ((b << 6) + ho) * 9;
    const uint4* pWb = paramsW + (size_t)pbase * 64 + (w << 4);
    const uint2* pAb = paramsA + (size_t)pbase * 64 + (w << 4);

#pragma unroll 1
    for (int n = 0; n < 9; ++n) {
        // --- W fragments: coalesced (1KB per instruction per wave) ---
        U16 wf[2][4];
#pragma unroll
        for (int ob = 0; ob < 2; ++ob)
#pragma unroll
            for (int ks = 0; ks < 4; ++ks)
                wf[ob][ks].u = wtv[(((n << 2) + ks) * 8 + (w << 1) + ob) * 64 + lane];
        const uint4* pW = pWb + n * 64;
        const uint2* pA = pAb + n * 64;
        int buf = n & 1;
        // --- gather + blend, 2 groups of 8 px ---
#pragma unroll 1
        for (int g = 0; g < 2; ++g) {
            u32 ld[8][4];
#pragma unroll
            for (int j = 0; j < 8; ++j) {
                uint2 aa = pA[(g << 3) + j];            // wave-uniform 8B load
                u32 a00 = aa.x, a11 = aa.y;
                u32 a01 = (a00 & ~0x3FFFu) | (a11 & 0x3FFFu);
                u32 a10 = (a11 & ~0x3FFFu) | (a00 & 0x3FFFu);
                ld[j][0] = *(const u32*)(xbb + a00 + lane4);
                ld[j][1] = *(const u32*)(xbb + a01 + lane4);
                ld[j][2] = *(const u32*)(xbb + a10 + lane4);
                ld[j][3] = *(const u32*)(xbb + a11 + lane4);
            }
#pragma unroll
            for (int j = 0; j < 8; ++j) {
                uint4 ww = pW[(g << 3) + j];            // wave-uniform 16B load
                u32 r = hfma2u(ld[j][3], ww.w, hfma2u(ld[j][2], ww.z,
                        hfma2u(ld[j][1], ww.y, hmul2u(ld[j][0], ww.x))));
                S[buf][(w << 4) + (g << 3) + j][lane] = r;
            }
        }
        __syncthreads();
        // --- MFMA: D[o][px] += W_tap * S_tap^T ---
#pragma unroll
        for (int ks = 0; ks < 4; ++ks) {
            U16 sf[4];
#pragma unroll
            for (int pb = 0; pb < 4; ++pb)
                sf[pb].u = *(const uint4*)&S[buf][pb * 16 + l15][(ks * 4 + lhi) << 2];
#pragma unroll
            for (int ob = 0; ob < 2; ++ob)
#pragma unroll
                for (int pb = 0; pb < 4; ++pb)
                    acc[ob][pb] = __builtin_amdgcn_mfma_f32_16x16x32_f16(
                        wf[ob][ks].h, sf[pb].h, acc[ob][pb], 0, 0, 0);
        }
    }
    // --- epilogue: o = o0+ob*16+lhi*4+r, px = pb*16+l15 ---
    float* ob_base = out + (size_t)b * 128 * HW_ + ho * 64;
#pragma unroll
    for (int ob = 0; ob < 2; ++ob)
#pragma unroll
        for (int r = 0; r < 4; ++r) {
            int o = o0 + ob * 16 + lhi * 4 + r;
            float bv = bias[o];
#pragma unroll
            for (int pb = 0; pb < 4; ++pb)
                ob_base[(size_t)o * HW_ + pb * 16 + l15] = acc[ob][pb][r] + bv;
        }
}

extern "C" void kernel_launch(void* const* d_in, const int* in_sizes, int n_in,
                              void* d_out, int out_size, void* d_ws, size_t ws_size,
                              hipStream_t stream) {
    const float* x      = (const float*)d_in[0];
    const float* weight = (const float*)d_in[1];
    const float* bias   = (const float*)d_in[2];
    const float* off_w  = (const float*)d_in[3];
    const float* off_b  = (const float*)d_in[4];
    float* out = (float*)d_out;

    // ws (u32 units): xtu 4194304 | offout 1769472 | wtv 73728 | woffu 18432
    //                 | paramsW 2359296 | paramsA 1179648   -> 38.4 MB
    u32*   xtu     = (u32*)d_ws;
    float* offout  = (float*)(xtu + (size_t)B_ * HW_ * CU_);
    uint4* wtv     = (uint4*)(offout + (size_t)B_ * 27 * HW_);
    u32*   woffu   = (u32*)wtv + 73728;
    uint4* paramsW = (uint4*)(woffu + 18432);
    uint2* paramsA = (uint2*)((u32*)paramsW + 2359296);

    hipLaunchKernelGGL(k_transpose, dim3(2048), dim3(256), 0, stream, x, xtu);
    hipLaunchKernelGGL(k_prep, dim3(144), dim3(256), 0, stream, weight, off_w, wtv, woffu);
    hipLaunchKernelGGL(k_offconv, dim3(1024), dim3(256), 0, stream, xtu, woffu, off_b, offout);
    hipLaunchKernelGGL(k_params, dim3(2304), dim3(256), 0, stream, offout, paramsW, paramsA);
    hipLaunchKernelGGL(k_fused, dim3(1024), dim3(256), 0, stream, xtu, wtv, paramsW, paramsA, bias, out);
}